// Round 2
// baseline (488.124 us; speedup 1.0000x reference)
//
#include <hip/hip_runtime.h>
#include <hip/hip_bf16.h>
#include <stdint.h>

using bf16x8 = __attribute__((ext_vector_type(8))) __bf16;
using bf16x4 = __attribute__((ext_vector_type(4))) __bf16;
using f32x4  = __attribute__((ext_vector_type(4))) float;

typedef const uint32_t __attribute__((address_space(1)))* gas_ptr;
typedef uint32_t __attribute__((address_space(3)))* las_ptr;

__device__ __forceinline__ void load_lds16(const void* g, void* l) {
    __builtin_amdgcn_global_load_lds((gas_ptr)g, (las_ptr)l, 16, 0, 0);
}

// cprelu post-normalization constants (PRELU_INIT = 0.25)
#define PM  0.29920671030107454f
#define PIS 1.5046096f
#define RHALF 0.70710678118654752f

// ---------------------------------------------------------------- k_prep
__global__ __launch_bounds__(256) void k_prep(const float* __restrict__ w1,
                                              const float* __restrict__ w2,
                                              const float* __restrict__ wm,
                                              const float* __restrict__ wsw,
                                              __bf16* __restrict__ W1p,
                                              __bf16* __restrict__ W2p,
                                              __bf16* __restrict__ WMp,
                                              __bf16* __restrict__ WSp)
{
    const int id = blockIdx.x * 256 + threadIdx.x;
    const int stride = gridDim.x * 256;
    for (int i = id; i < 96 * 64; i += stride) {
        int oc = i >> 6, ic = i & 63;
        W1p[i] = (__bf16)((oc < 83) ? w1[oc * 64 + ic] : 0.f);
    }
    for (int i = id; i < 112 * 96; i += stride) {
        int oc = i / 96, ic = i % 96;
        W2p[i] = (__bf16)((oc < 102 && ic < 83) ? w2[oc * 83 + ic] : 0.f);
    }
    for (int i = id; i < 128 * 128; i += stride) {
        int oc = i >> 7, ic = i & 127;
        WMp[i] = (__bf16)((ic < 102) ? wm[oc * 102 + ic] : 0.f);
    }
    for (int i = id; i < 128 * 64; i += stride) {
        WSp[i] = (__bf16)wsw[i];
    }
}

// ---------------------------------------------------------------- k_conv
// Fused: conn fp32 -> bf16 (row-private, read-all-then-write so in-place is
// safe) + per-row max + tie-index collection (exact fp32 equality, cap 16).
__global__ __launch_bounds__(256) void k_conv(const float* __restrict__ conn,
                                              __bf16* __restrict__ cb,
                                              size_t rowstride,
                                              int* __restrict__ cnt,
                                              int* __restrict__ idx)
{
    const int o = blockIdx.x;
    const int t = threadIdx.x;
    const float* row = conn + (size_t)o * 8192;
    float4 v[8];
    float m = -1e30f;
#pragma unroll
    for (int q = 0; q < 8; q++) {
        v[q] = *(const float4*)(row + (size_t)(q * 256 + t) * 4);
        m = fmaxf(m, fmaxf(fmaxf(v[q].x, v[q].y), fmaxf(v[q].z, v[q].w)));
    }
    __syncthreads();   // all reads drained before in-place overwrite
    __bf16* drow = cb + (size_t)o * rowstride;
#pragma unroll
    for (int q = 0; q < 8; q++) {
        bf16x4 w;
        w[0] = (__bf16)v[q].x; w[1] = (__bf16)v[q].y;
        w[2] = (__bf16)v[q].z; w[3] = (__bf16)v[q].w;
        *(bf16x4*)(drow + (size_t)(q * 256 + t) * 4) = w;
    }
#pragma unroll
    for (int off = 32; off > 0; off >>= 1) m = fmaxf(m, __shfl_down(m, off, 64));
    __shared__ float wmax[4];
    __shared__ int scnt;
    if ((t & 63) == 0) wmax[t >> 6] = m;
    if (t == 0) scnt = 0;
    __syncthreads();
    const float rmax = fmaxf(fmaxf(wmax[0], wmax[1]), fmaxf(wmax[2], wmax[3]));
#pragma unroll
    for (int q = 0; q < 8; q++) {
        float vv[4] = {v[q].x, v[q].y, v[q].z, v[q].w};
#pragma unroll
        for (int e = 0; e < 4; e++) {
            if (vv[e] >= rmax) {
                int p = atomicAdd(&scnt, 1);
                if (p < 16) idx[o * 16 + p] = (q * 256 + t) * 4 + e;
            }
        }
    }
    __syncthreads();
    if (t == 0) cnt[o] = scnt < 16 ? scnt : 16;
}

// ---------------------------------------------------------------- k_chain
template<int KS>
__device__ __forceinline__ f32x4 mfma_tile(const __bf16* __restrict__ W, int wstride, int mt,
                                           const __bf16* B, int bstride, int nt, int lane)
{
    f32x4 acc = {0.f, 0.f, 0.f, 0.f};
    const int l15 = lane & 15;
    const int kg  = (lane >> 4) << 3;
    const __bf16* wp = W + (mt * 16 + l15) * wstride + kg;
    const __bf16* bp = B + (nt * 16 + l15) * bstride + kg;
#pragma unroll
    for (int ks = 0; ks < KS; ks++) {
        bf16x8 av = *(const bf16x8*)(wp + ks * 32);
        bf16x8 bv = *(const bf16x8*)(bp + ks * 32);
        acc = __builtin_amdgcn_mfma_f32_16x16x32_bf16(av, bv, acc, 0, 0, 0);
    }
    return acc;
}

__global__ __launch_bounds__(256) void k_chain(
    const float* __restrict__ x,
    const float* __restrict__ b1, const float* __restrict__ p1,
    const float* __restrict__ b2, const float* __restrict__ p2,
    const float* __restrict__ bm, const float* __restrict__ bs,
    const __bf16* __restrict__ W1p, const __bf16* __restrict__ W2p,
    const __bf16* __restrict__ WMp, const __bf16* __restrict__ WSp,
    __bf16* __restrict__ h3, __bf16* __restrict__ s_t)
{
    __shared__ __bf16 buf0[64 * 136];   // Xt (stride 72) then H2t (stride 136)
    __shared__ __bf16 un[128 * 72];     // H1t (stride 104) then OutT (stride 72)
    __shared__ float  bl[672];
    __bf16* H1t  = un;                  // 64 x 104 fits in 128*72
    __bf16* OutT = un;                  // 128 x 72
    float* b1l = bl;       float* p1l = bl + 96;
    float* b2l = bl + 192; float* p2l = bl + 304;
    float* bml = bl + 416; float* bsl = bl + 544;

    const int t = threadIdx.x, lane = t & 63, wid = t >> 6;
    const int b = blockIdx.y;
    const int p0 = blockIdx.x * 64;

    for (int i = t; i < 96; i += 256)  { b1l[i] = (i < 83)  ? b1[i] : 0.f; p1l[i] = (i < 83)  ? p1[i] : 0.f; }
    for (int i = t; i < 112; i += 256) { b2l[i] = (i < 102) ? b2[i] : 0.f; p2l[i] = (i < 102) ? p2[i] : 0.f; }
    for (int i = t; i < 128; i += 256) { bml[i] = bm[i]; bsl[i] = bs[i]; }

    {
        const int p = t & 63;
        const int cg = t >> 6;     // 0..3
#pragma unroll 4
        for (int it = 0; it < 16; it++) {
            int c = it * 4 + cg;
            buf0[p * 72 + c] = (__bf16)x[((size_t)b * 64 + c) * 8192 + p0 + p];
        }
    }
    __syncthreads();

    const int quad4 = (lane >> 4) << 2;
    const int l15 = lane & 15;

    // shortcut S = WS*X + bs  (8 mt x 4 nt)
    for (int tt = wid; tt < 32; tt += 4) {
        int mt = tt >> 2, nt = tt & 3;
        f32x4 a = mfma_tile<2>(WSp, 64, mt, buf0, 72, nt, lane);
        int ocb = mt * 16 + quad4;
        int pos = nt * 16 + l15;
        bf16x4 ov;
#pragma unroll
        for (int r = 0; r < 4; r++) ov[r] = (__bf16)(a[r] + bsl[ocb + r]);
        *(bf16x4*)(s_t + ((size_t)b * 8192 + p0 + pos) * 128 + ocb) = ov;
    }
    // H1 = cprelu(W1*X + b1)  (6 mt x 4 nt)
    for (int tt = wid; tt < 24; tt += 4) {
        int mt = tt >> 2, nt = tt & 3;
        f32x4 a = mfma_tile<2>(W1p, 64, mt, buf0, 72, nt, lane);
        int ocb = mt * 16 + quad4;
        int pos = nt * 16 + l15;
        bf16x4 ov;
#pragma unroll
        for (int r = 0; r < 4; r++) {
            float v = a[r] + b1l[ocb + r];
            v = (v >= 0.f) ? v : v * p1l[ocb + r];
            ov[r] = (__bf16)((v - PM) * PIS);
        }
        *(bf16x4*)(&H1t[pos * 104 + ocb]) = ov;
    }
    __syncthreads();

    // H2 = cprelu(W2*H1 + b2)  (7 mt x 4 nt), into buf0 (Xt dead)
    for (int tt = wid; tt < 28; tt += 4) {
        int mt = tt >> 2, nt = tt & 3;
        f32x4 a = mfma_tile<3>(W2p, 96, mt, H1t, 104, nt, lane);
        int ocb = mt * 16 + quad4;
        int pos = nt * 16 + l15;
        bf16x4 ov;
#pragma unroll
        for (int r = 0; r < 4; r++) {
            float v = a[r] + b2l[ocb + r];
            v = (v >= 0.f) ? v : v * p2l[ocb + r];
            ov[r] = (__bf16)((v - PM) * PIS);
        }
        *(bf16x4*)(&buf0[pos * 136 + ocb]) = ov;
    }
    // zero H2 pad channels 112..127
    for (int i = t; i < 64 * 16; i += 256) {
        int pos = i >> 4, c = 112 + (i & 15);
        buf0[pos * 136 + c] = (__bf16)0.f;
    }
    __syncthreads();   // also: H1t reads done before OutT overwrites region

    // H3 = WM*H2 + bm  (8 mt x 4 nt) -> OutT[ch][pos] in LDS
    for (int tt = wid; tt < 32; tt += 4) {
        int mt = tt >> 2, nt = tt & 3;
        f32x4 a = mfma_tile<4>(WMp, 128, mt, buf0, 136, nt, lane);
        int ocb = mt * 16 + quad4;
        int pos = nt * 16 + l15;
#pragma unroll
        for (int r = 0; r < 4; r++)
            OutT[(ocb + r) * 72 + pos] = (__bf16)(a[r] + bml[ocb + r]);
    }
    __syncthreads();

    // coalesced OutT -> h3 (bf16x8 per lane, 128B per channel row)
#pragma unroll
    for (int it = 0; it < 4; it++) {
        int lin = it * 256 + t;       // 0..1023
        int ch = lin >> 3, pc = lin & 7;
        bf16x8 v = *(const bf16x8*)(OutT + ch * 72 + pc * 8);
        *(bf16x8*)(h3 + ((size_t)b * 128 + ch) * 8192 + p0 + pc * 8) = v;
    }
}

// ---------------------------------------------------------------- k_gemm
// C[2048,4096] = A[2048,8192](bf16) x B[4096,bstride](bf16, N x K rows)
// 256x256 tile, BK=64, 8 waves (2M x 4N), 8-phase counted-vmcnt schedule.
// LDS 128 KiB double-buffered. Swizzle: 16B chunk c of a 64-elem row r
// stored at slot c ^ (r & 7); inverse applied on the global SOURCE address
// so the global_load_lds destination stays linear.
//
// R2 schedule (no sched_barrier pinning — m141; reads spread 12/4/8/0):
//   P1: ds_read af0(8)+bfr01(4) ; stage (t+1).B h0 -> ~d ; bar ; MFMA m0-3 x n0-1 ; lgkm0 ; bar
//   P2: ds_read bfr23(4)        ; stage (t+1).B h1 -> ~d ; bar ; MFMA m0-3 x n2-3 ; lgkm0 ; bar
//   P3: ds_read af1(8)          ;                         bar ; MFMA m4-7 x n0-1 ; lgkm0 ; bar
//   P4:                           stage (t+2).A h0+h1 -> d ; bar ; MFMA m4-7 x n2-3 ; vmcnt(4) ; bar
// WAR: explicit lgkmcnt(0) before each closing barrier guarantees all this
// phase's ds_reads completed (into regs) before any wave can issue the next
// LDS-DMA stage into the buffer just read — regardless of where the compiler
// schedules the register-only MFMAs. RAW: fragment loads are C++-level, so
// compiler inserts the lgkm waits feeding MFMAs; vmcnt(4) at P4 retires tile
// t+1's A+B (8 loads), leaving only tile t+2's A (4) in flight.
#define GFENCE() asm volatile("" ::: "memory")
#define GBAR()   do { GFENCE(); __builtin_amdgcn_s_barrier(); GFENCE(); } while (0)
#define LGKM0()  asm volatile("s_waitcnt lgkmcnt(0)" ::: "memory")

__global__ __launch_bounds__(512, 2) void k_gemm(const __bf16* __restrict__ A,
                                                 const __bf16* __restrict__ B,
                                                 size_t bstride,
                                                 float* __restrict__ C0,
                                                 float* __restrict__ C1,
                                                 int KH)
{
    __shared__ __bf16 la[2][256 * 64];
    __shared__ __bf16 lb[2][256 * 64];

    const int t = threadIdx.x;          // 0..511
    const int lane = t & 63;
    const int wid = t >> 6;             // 0..7
    const int wm = wid >> 2;            // 0..1  M half (128 rows)
    const int wn = wid & 3;             // 0..3  N quarter (64 cols)

    // bijective XCD swizzle (nwg=128, 128%8==0): each XCD gets 16 consecutive
    // swizzled ids = 2 N-panels (4 MB of B = one L2) x 8 M-panels.
    const int orig = blockIdx.x;                   // 0..127
    const int swz  = (orig & 7) * 16 + (orig >> 3);
    const int tN = (swz >> 3) * 256;               // 0..15 -> N tile
    const int tM = (swz & 7) * 256;                // 0..7  -> M tile
    const int kz = blockIdx.z;
    const int k0 = kz * KH;
    float* __restrict__ C = kz ? C1 : C0;

    // ---- staging addresses (pre-swizzled source, linear LDS dest) ----
    const int rA = t >> 3;                    // row within 64-row issue group
    const int cA = (t & 7) ^ (rA & 7);        // swizzled source chunk
    const __bf16* pA0 = A + (size_t)(tM + rA) * 8192 + k0 + cA * 8;
    const __bf16* pA1 = pA0 + (size_t)128 * 8192;
    const __bf16* pB0 = B + (size_t)(tN + rA) * bstride + k0 + cA * 8;
    const __bf16* pB1 = pB0 + (size_t)128 * bstride;
    const size_t iA = (size_t)64 * 8192;      // second-issue source offset
    const size_t iB = (size_t)64 * bstride;

#define STG_A(d, h, kk) do { \
    const __bf16* s_ = ((h) ? pA1 : pA0) + (kk); \
    __bf16* l_ = &la[d][(h) * 8192 + t * 8]; \
    load_lds16(s_, l_); \
    load_lds16(s_ + iA, l_ + 4096); } while (0)
#define STG_B(d, h, kk) do { \
    const __bf16* s_ = ((h) ? pB1 : pB0) + (kk); \
    __bf16* l_ = &lb[d][(h) * 8192 + t * 8]; \
    load_lds16(s_, l_); \
    load_lds16(s_ + iB, l_ + 4096); } while (0)

    // ---- fragment read offsets (elements within la[d]/lb[d]) ----
    const int l15 = lane & 15;
    const int q = lane >> 4;
    int aofs[2], bofs[2];
#pragma unroll
    for (int ks = 0; ks < 2; ks++) {
        int sw = ((ks * 4 + q) ^ (l15 & 7)) * 8;
        aofs[ks] = (wm * 128 + l15) * 64 + sw;
        bofs[ks] = (wn * 64  + l15) * 64 + sw;
    }
#define LDA(d, m, ks) (*(const bf16x8*)(&la[d][aofs[ks] + (m) * 1024]))
#define LDB(d, n, ks) (*(const bf16x8*)(&lb[d][bofs[ks] + (n) * 1024]))

    f32x4 acc[8][4];
    const f32x4 zero = {0.f, 0.f, 0.f, 0.f};
#pragma unroll
    for (int m = 0; m < 8; m++)
#pragma unroll
        for (int n = 0; n < 4; n++) acc[m][n] = zero;

    bf16x8 af0[4][2], af1[4][2], bfr[4][2];

#define CLUSTER(M0, N0, AF) do { \
    __builtin_amdgcn_s_setprio(1); \
    _Pragma("unroll") \
    for (int ks_ = 0; ks_ < 2; ks_++) \
        _Pragma("unroll") \
        for (int m_ = 0; m_ < 4; m_++) \
            _Pragma("unroll") \
            for (int n_ = 0; n_ < 2; n_++) \
                acc[(M0) + m_][(N0) + n_] = __builtin_amdgcn_mfma_f32_16x16x32_bf16( \
                    AF[m_][ks_], bfr[(N0) + n_][ks_], acc[(M0) + m_][(N0) + n_], 0, 0, 0); \
    __builtin_amdgcn_s_setprio(0); \
} while (0)

#define TILE_STEP(d, kkB, kkA) do { \
    /* P1: af0 + bfr01 ; stage B(t+1) h0 */ \
    _Pragma("unroll") \
    for (int m_ = 0; m_ < 4; m_++) { af0[m_][0] = LDA(d, m_, 0); af0[m_][1] = LDA(d, m_, 1); } \
    _Pragma("unroll") \
    for (int n_ = 0; n_ < 2; n_++) { bfr[n_][0] = LDB(d, n_, 0); bfr[n_][1] = LDB(d, n_, 1); } \
    STG_B(1 - (d), 0, kkB); \
    GBAR(); \
    CLUSTER(0, 0, af0); \
    LGKM0(); \
    GBAR(); \
    /* P2: bfr23 ; stage B(t+1) h1 */ \
    _Pragma("unroll") \
    for (int n_ = 2; n_ < 4; n_++) { bfr[n_][0] = LDB(d, n_, 0); bfr[n_][1] = LDB(d, n_, 1); } \
    STG_B(1 - (d), 1, kkB); \
    GBAR(); \
    CLUSTER(0, 2, af0); \
    LGKM0(); \
    GBAR(); \
    /* P3: af1 ; no stage */ \
    _Pragma("unroll") \
    for (int m_ = 0; m_ < 4; m_++) { af1[m_][0] = LDA(d, 4 + m_, 0); af1[m_][1] = LDA(d, 4 + m_, 1); } \
    GBAR(); \
    CLUSTER(4, 0, af1); \
    LGKM0(); \
    GBAR(); \
    /* P4: stage A(t+2) h0+h1 into d */ \
    STG_A(d, 0, kkA); \
    STG_A(d, 1, kkA); \
    GBAR(); \
    CLUSTER(4, 2, af1); \
    asm volatile("s_waitcnt vmcnt(4)" ::: "memory"); \
    GBAR(); \
} while (0)

    // ---- prologue: tile0 complete + tile1 A halves ----
    STG_A(0, 0, 0); STG_A(0, 1, 0);
    STG_B(0, 0, 0); STG_B(0, 1, 0);
    STG_A(1, 0, 64); STG_A(1, 1, 64);
    asm volatile("s_waitcnt vmcnt(4)" ::: "memory");   // tile0 landed
    GBAR();

    const int NT = KH >> 6;                 // 64 (split) or 128 (no split)
    for (int itp = 0; itp < (NT >> 1); ++itp) {
        const int a = 2 * itp;
        const int kkB_b = (a + 1) << 6;                       // always < KH
        int kkA_a2 = (a + 2) << 6; if (kkA_a2 >= KH) kkA_a2 -= KH;   // wrap: harmless refetch
        int kkA_b2 = (a + 3) << 6; if (kkA_b2 >= KH) kkA_b2 -= KH;
        TILE_STEP(0, kkB_b, kkA_a2);        // compute tile a   from buf0
        TILE_STEP(1, kkA_a2, kkA_b2);       // compute tile a+1 from buf1
    }

    asm volatile("s_waitcnt vmcnt(0)" ::: "memory");   // drain tail LDS-DMA before endpgm/stores

    // ---- epilogue: wave (wm,wn) owns C rows [tM+wm*128,+128) cols [tN+wn*64,+64)
    const int quad4 = q * 4;
#pragma unroll
    for (int m = 0; m < 8; m++) {
        int gm = tM + wm * 128 + m * 16 + quad4;
#pragma unroll
        for (int n = 0; n < 4; n++) {
            int gn = tN + wn * 64 + n * 16 + l15;
#pragma unroll
            for (int r = 0; r < 4; r++)
                C[(size_t)(gm + r) * 4096 + gn] = acc[m][n][r];
        }
    }
#undef TILE_STEP
#undef CLUSTER
#undef LDA
#undef LDB
#undef STG_A
#undef STG_B
}

// ---------------------------------------------------------------- k_combine
__global__ __launch_bounds__(256) void k_combine(float* __restrict__ out,
                                                 const float* __restrict__ P1,
                                                 int nsplit,
                                                 const __bf16* __restrict__ s_t,
                                                 const int* __restrict__ idx,
                                                 const int* __restrict__ cnt,
                                                 const float* __restrict__ p3)
{
    __shared__ float sp[64][133];
    const int b = blockIdx.y;
    const int o0 = blockIdx.x * 64;
    const int t = threadIdx.x;

    {
        const int ol = t >> 2;
        const int part = t & 3;
        const int o = o0 + ol;
        const int n = cnt[o];
        float acc[32];
#pragma unroll
        for (int j = 0; j < 32; j++) acc[j] = 0.f;
        for (int k = 0; k < n; k++) {
            const int i = idx[o * 16 + k];
            const __bf16* row = s_t + ((size_t)b * 8192 + i) * 128 + part * 32;
#pragma unroll
            for (int j = 0; j < 32; j += 8) {
                bf16x8 v = *(const bf16x8*)(row + j);
#pragma unroll
                for (int u = 0; u < 8; u++) acc[j + u] += (float)v[u];
            }
        }
#pragma unroll
        for (int j = 0; j < 32; j++) sp[ol][part * 32 + j] = acc[j];
    }
    __syncthreads();

    if (nsplit == 2) {
        for (int rr = 0; rr < 32; rr++) {
            const int c = rr * 4 + (t >> 6);
            const int o = t & 63;
            const size_t oi = ((size_t)b * 128 + c) * 4096 + o0 + o;
            float v = out[oi] + P1[oi];
            const float pw = p3[c];
            float y = (v >= 0.f) ? v : v * pw;
            y = (y - PM) * PIS;
            out[oi] = sp[o][c] * RHALF + y * RHALF;
        }
    } else {
        for (int rr = 0; rr < 32; rr++) {
            const int c = rr * 4 + (t >> 6);
            const int o = t & 63;
            const size_t oi = ((size_t)b * 128 + c) * 4096 + o0 + o;
            float v = out[oi];
            const float pw = p3[c];
            float y = (v >= 0.f) ? v : v * pw;
            y = (y - PM) * PIS;
            out[oi] = sp[o][c] * RHALF + y * RHALF;
        }
    }
}

// ---------------------------------------------------------------- launch
extern "C" void kernel_launch(void* const* d_in, const int* in_sizes, int n_in,
                              void* d_out, int out_size, void* d_ws, size_t ws_size,
                              hipStream_t stream) {
    (void)in_sizes; (void)n_in; (void)out_size;
    const float* x    = (const float*)d_in[0];
    const float* conn = (const float*)d_in[1];
    const float* w1   = (const float*)d_in[2];
    const float* b1   = (const float*)d_in[3];
    const float* p1   = (const float*)d_in[4];
    const float* w2   = (const float*)d_in[5];
    const float* b2   = (const float*)d_in[6];
    const float* p2   = (const float*)d_in[7];
    const float* wm   = (const float*)d_in[8];
    const float* bm   = (const float*)d_in[9];
    const float* p3   = (const float*)d_in[10];
    const float* wsw  = (const float*)d_in[11];
    const float* bs   = (const float*)d_in[12];
    float* out = (float*)d_out;

    char* ws = (char*)d_ws;
    __bf16* h3  = (__bf16*)(ws);                          // 33,554,432 B
    __bf16* s_t = (__bf16*)(ws + 33554432);               // 33,554,432 B
    __bf16* W1p = (__bf16*)(ws + 67108864);               // 12,288
    __bf16* W2p = (__bf16*)(ws + 67108864 + 12288);       // 21,504
    __bf16* WMp = (__bf16*)(ws + 67108864 + 33792);       // 32,768
    __bf16* WSp = (__bf16*)(ws + 67108864 + 66560);       // 16,384
    int* idx = (int*)(ws + 67108864 + 82944);             // 262,144
    int* cnt = (int*)(ws + 67108864 + 82944 + 262144);    // 16,384
    const size_t p1_off    = 67108864 + 82944 + 262144 + 16384;   // 67,470,336
    float* Pk1 = (float*)(ws + p1_off);                   // 33,554,432
    const size_t connb_off = p1_off + 33554432;           // 101,024,768

    __bf16* connb;
    size_t  cstride;
    if (ws_size >= connb_off + (size_t)4096 * 8192 * 2) {
        connb = (__bf16*)(ws + connb_off);
        cstride = 8192;
    } else {
        connb = (__bf16*)const_cast<float*>(conn);
        cstride = 16384;   // bf16 row packed into first half of its fp32 row
    }
    const int nsplit = (ws_size >= p1_off + 33554432) ? 2 : 1;
    const int KH = 8192 / nsplit;

    k_prep<<<32, 256, 0, stream>>>(w1, w2, wm, wsw, W1p, W2p, WMp, WSp);
    k_conv<<<4096, 256, 0, stream>>>(conn, connb, cstride, cnt, idx);
    k_chain<<<dim3(8192 / 64, 16), 256, 0, stream>>>(x, b1, p1, b2, p2, bm, bs,
                                                     W1p, W2p, WMp, WSp, h3, s_t);
    k_gemm<<<dim3(128, 1, nsplit), 512, 0, stream>>>(h3, connb, cstride, out, Pk1, KH);
    k_combine<<<dim3(4096 / 64, 16), 256, 0, stream>>>(out, Pk1, nsplit, s_t, idx, cnt, p3);
}

// Round 3
// 467.111 us; speedup vs baseline: 1.0450x; 1.0450x over previous
//
#include <hip/hip_runtime.h>
#include <hip/hip_bf16.h>
#include <stdint.h>

using bf16x8 = __attribute__((ext_vector_type(8))) __bf16;
using bf16x4 = __attribute__((ext_vector_type(4))) __bf16;
using f32x4  = __attribute__((ext_vector_type(4))) float;

typedef const uint32_t __attribute__((address_space(1)))* gas_ptr;
typedef uint32_t __attribute__((address_space(3)))* las_ptr;

__device__ __forceinline__ void load_lds16(const void* g, void* l) {
    __builtin_amdgcn_global_load_lds((gas_ptr)g, (las_ptr)l, 16, 0, 0);
}

// cprelu post-normalization constants (PRELU_INIT = 0.25)
#define PM  0.29920671030107454f
#define PIS 1.5046096f
#define RHALF 0.70710678118654752f

// ---------------------------------------------------------------- k_prep
__global__ __launch_bounds__(256) void k_prep(const float* __restrict__ w1,
                                              const float* __restrict__ w2,
                                              const float* __restrict__ wm,
                                              const float* __restrict__ wsw,
                                              __bf16* __restrict__ W1p,
                                              __bf16* __restrict__ W2p,
                                              __bf16* __restrict__ WMp,
                                              __bf16* __restrict__ WSp)
{
    const int id = blockIdx.x * 256 + threadIdx.x;
    const int stride = gridDim.x * 256;
    for (int i = id; i < 96 * 64; i += stride) {
        int oc = i >> 6, ic = i & 63;
        W1p[i] = (__bf16)((oc < 83) ? w1[oc * 64 + ic] : 0.f);
    }
    for (int i = id; i < 112 * 96; i += stride) {
        int oc = i / 96, ic = i % 96;
        W2p[i] = (__bf16)((oc < 102 && ic < 83) ? w2[oc * 83 + ic] : 0.f);
    }
    for (int i = id; i < 128 * 128; i += stride) {
        int oc = i >> 7, ic = i & 127;
        WMp[i] = (__bf16)((ic < 102) ? wm[oc * 102 + ic] : 0.f);
    }
    for (int i = id; i < 128 * 64; i += stride) {
        WSp[i] = (__bf16)wsw[i];
    }
}

// ---------------------------------------------------------------- mfma_tile
template<int KS>
__device__ __forceinline__ f32x4 mfma_tile(const __bf16* __restrict__ W, int wstride, int mt,
                                           const __bf16* B, int bstride, int nt, int lane)
{
    f32x4 acc = {0.f, 0.f, 0.f, 0.f};
    const int l15 = lane & 15;
    const int kg  = (lane >> 4) << 3;
    const __bf16* wp = W + (mt * 16 + l15) * wstride + kg;
    const __bf16* bp = B + (nt * 16 + l15) * bstride + kg;
#pragma unroll
    for (int ks = 0; ks < KS; ks++) {
        bf16x8 av = *(const bf16x8*)(wp + ks * 32);
        bf16x8 bv = *(const bf16x8*)(bp + ks * 32);
        acc = __builtin_amdgcn_mfma_f32_16x16x32_bf16(av, bv, acc, 0, 0, 0);
    }
    return acc;
}

// ---------------------------------------------------------------- k_cc
// Fused k_conv (4096 blocks) + k_chain (2048 blocks), grid-partitioned and
// interleaved 2:1 (conv,conv,chain) so memory-bound conv co-schedules with
// latency/MFMA-bound chain. Both paths are independent; branch is uniform
// per block so __syncthreads inside branches is safe. LDS via shared pool
// (38528 B = chain's requirement; conv uses 20 B of it).
__global__ __launch_bounds__(256) void k_cc(
    // conv args
    const float* __restrict__ conn, __bf16* __restrict__ cb, size_t rowstride,
    int* __restrict__ cnt, int* __restrict__ idx,
    // chain args
    const float* __restrict__ x,
    const float* __restrict__ b1, const float* __restrict__ p1,
    const float* __restrict__ b2, const float* __restrict__ p2,
    const float* __restrict__ bm, const float* __restrict__ bs,
    const __bf16* __restrict__ W1p, const __bf16* __restrict__ W2p,
    const __bf16* __restrict__ WMp, const __bf16* __restrict__ WSp,
    __bf16* __restrict__ h3, __bf16* __restrict__ s_t)
{
    __shared__ __align__(16) char pool[38528];
    const int t = threadIdx.x;
    const int bx = blockIdx.x;
    const int r3 = bx % 3;
    const int g  = bx / 3;

    if (r3 < 2) {
        // ------------------------------------------------ conv path
        const int o = 2 * g + r3;              // 0..4095
        float* wmax = (float*)pool;            // 16 B
        int*   scnt = (int*)(pool + 16);
        const float* row = conn + (size_t)o * 8192;
        float4 v[8];
        float m = -1e30f;
#pragma unroll
        for (int q = 0; q < 8; q++) {
            v[q] = *(const float4*)(row + (size_t)(q * 256 + t) * 4);
            m = fmaxf(m, fmaxf(fmaxf(v[q].x, v[q].y), fmaxf(v[q].z, v[q].w)));
        }
        __syncthreads();   // all reads drained before in-place overwrite
        __bf16* drow = cb + (size_t)o * rowstride;
#pragma unroll
        for (int q = 0; q < 8; q++) {
            bf16x4 w;
            w[0] = (__bf16)v[q].x; w[1] = (__bf16)v[q].y;
            w[2] = (__bf16)v[q].z; w[3] = (__bf16)v[q].w;
            *(bf16x4*)(drow + (size_t)(q * 256 + t) * 4) = w;
        }
#pragma unroll
        for (int off = 32; off > 0; off >>= 1) m = fmaxf(m, __shfl_down(m, off, 64));
        if ((t & 63) == 0) wmax[t >> 6] = m;
        if (t == 0) *scnt = 0;
        __syncthreads();
        const float rmax = fmaxf(fmaxf(wmax[0], wmax[1]), fmaxf(wmax[2], wmax[3]));
#pragma unroll
        for (int q = 0; q < 8; q++) {
            float vv[4] = {v[q].x, v[q].y, v[q].z, v[q].w};
#pragma unroll
            for (int e = 0; e < 4; e++) {
                if (vv[e] >= rmax) {
                    int p = atomicAdd(scnt, 1);
                    if (p < 16) idx[o * 16 + p] = (q * 256 + t) * 4 + e;
                }
            }
        }
        __syncthreads();
        if (t == 0) cnt[o] = *scnt < 16 ? *scnt : 16;
        return;
    }

    // ---------------------------------------------------- chain path
    const int b  = g >> 7;                 // 0..15
    const int p0 = (g & 127) * 64;         // 0..8128
    __bf16* buf0 = (__bf16*)pool;          // 64*136 = 17408 B
    __bf16* un   = (__bf16*)(pool + 17408);// 128*72 = 18432 B
    float*  bl   = (float*)(pool + 35840); // 672 floats = 2688 B
    __bf16* H1t  = un;                     // 64 x 104 fits in 128*72
    __bf16* OutT = un;                     // 128 x 72
    float* b1l = bl;       float* p1l = bl + 96;
    float* b2l = bl + 192; float* p2l = bl + 304;
    float* bml = bl + 416; float* bsl = bl + 544;

    const int lane = t & 63, wid = t >> 6;

    for (int i = t; i < 96; i += 256)  { b1l[i] = (i < 83)  ? b1[i] : 0.f; p1l[i] = (i < 83)  ? p1[i] : 0.f; }
    for (int i = t; i < 112; i += 256) { b2l[i] = (i < 102) ? b2[i] : 0.f; p2l[i] = (i < 102) ? p2[i] : 0.f; }
    for (int i = t; i < 128; i += 256) { bml[i] = bm[i]; bsl[i] = bs[i]; }

    {
        const int p = t & 63;
        const int cg = t >> 6;     // 0..3
#pragma unroll 4
        for (int it = 0; it < 16; it++) {
            int c = it * 4 + cg;
            buf0[p * 72 + c] = (__bf16)x[((size_t)b * 64 + c) * 8192 + p0 + p];
        }
    }
    __syncthreads();

    const int quad4 = (lane >> 4) << 2;
    const int l15 = lane & 15;

    // shortcut S = WS*X + bs  (8 mt x 4 nt)
    for (int tt = wid; tt < 32; tt += 4) {
        int mt = tt >> 2, nt = tt & 3;
        f32x4 a = mfma_tile<2>(WSp, 64, mt, buf0, 72, nt, lane);
        int ocb = mt * 16 + quad4;
        int pos = nt * 16 + l15;
        bf16x4 ov;
#pragma unroll
        for (int r = 0; r < 4; r++) ov[r] = (__bf16)(a[r] + bsl[ocb + r]);
        *(bf16x4*)(s_t + ((size_t)b * 8192 + p0 + pos) * 128 + ocb) = ov;
    }
    // H1 = cprelu(W1*X + b1)  (6 mt x 4 nt)
    for (int tt = wid; tt < 24; tt += 4) {
        int mt = tt >> 2, nt = tt & 3;
        f32x4 a = mfma_tile<2>(W1p, 64, mt, buf0, 72, nt, lane);
        int ocb = mt * 16 + quad4;
        int pos = nt * 16 + l15;
        bf16x4 ov;
#pragma unroll
        for (int r = 0; r < 4; r++) {
            float v = a[r] + b1l[ocb + r];
            v = (v >= 0.f) ? v : v * p1l[ocb + r];
            ov[r] = (__bf16)((v - PM) * PIS);
        }
        *(bf16x4*)(&H1t[pos * 104 + ocb]) = ov;
    }
    __syncthreads();

    // H2 = cprelu(W2*H1 + b2)  (7 mt x 4 nt), into buf0 (Xt dead)
    for (int tt = wid; tt < 28; tt += 4) {
        int mt = tt >> 2, nt = tt & 3;
        f32x4 a = mfma_tile<3>(W2p, 96, mt, H1t, 104, nt, lane);
        int ocb = mt * 16 + quad4;
        int pos = nt * 16 + l15;
        bf16x4 ov;
#pragma unroll
        for (int r = 0; r < 4; r++) {
            float v = a[r] + b2l[ocb + r];
            v = (v >= 0.f) ? v : v * p2l[ocb + r];
            ov[r] = (__bf16)((v - PM) * PIS);
        }
        *(bf16x4*)(&buf0[pos * 136 + ocb]) = ov;
    }
    // zero H2 pad channels 112..127
    for (int i = t; i < 64 * 16; i += 256) {
        int pos = i >> 4, c = 112 + (i & 15);
        buf0[pos * 136 + c] = (__bf16)0.f;
    }
    __syncthreads();   // also: H1t reads done before OutT overwrites region

    // H3 = WM*H2 + bm  (8 mt x 4 nt) -> OutT[ch][pos] in LDS
    for (int tt = wid; tt < 32; tt += 4) {
        int mt = tt >> 2, nt = tt & 3;
        f32x4 a = mfma_tile<4>(WMp, 128, mt, buf0, 136, nt, lane);
        int ocb = mt * 16 + quad4;
        int pos = nt * 16 + l15;
#pragma unroll
        for (int r = 0; r < 4; r++)
            OutT[(ocb + r) * 72 + pos] = (__bf16)(a[r] + bml[ocb + r]);
    }
    __syncthreads();

    // coalesced OutT -> h3 (bf16x8 per lane, 128B per channel row)
#pragma unroll
    for (int it = 0; it < 4; it++) {
        int lin = it * 256 + t;       // 0..1023
        int ch = lin >> 3, pc = lin & 7;
        bf16x8 v = *(const bf16x8*)(OutT + ch * 72 + pc * 8);
        *(bf16x8*)(h3 + ((size_t)b * 128 + ch) * 8192 + p0 + pc * 8) = v;
    }
}

// ---------------------------------------------------------------- k_gemm
// out[2048,4096] = combine(A[2048,8192](bf16) x B[4096,bstride](bf16)).
// r0-proven 128x128 tile, BK=64 (32KB LDS), full K=8192 (no split-K).
// XOR swizzle: 16B chunk (row, c) of a 64-elem row stored at c ^ (row & 7).
// Epilogue fusion: tM spans exactly one batch's 128 channels, so the block
// holds the complete C tile -> apply cprelu(p3), gather sp from s_t via
// idx/cnt (argmax pooling of shortcut), blend, write final out. This
// removes k_combine and the Pk1/out HBM round-trips (~128 MB).
// LDS pool: la+lb (32 KB) during K-loop, then reused as sp[128][129]+p3l.
__global__ __launch_bounds__(256, 2) void k_gemm(const __bf16* __restrict__ A,
                                                 const __bf16* __restrict__ B,
                                                 size_t bstride,
                                                 float* __restrict__ out,
                                                 const __bf16* __restrict__ s_t,
                                                 const int* __restrict__ idx,
                                                 const int* __restrict__ cnt,
                                                 const float* __restrict__ p3)
{
    __shared__ __align__(16) char pool[66560];
    __bf16* la = (__bf16*)pool;              // 128*64 bf16 = 16384 B
    __bf16* lb = (__bf16*)(pool + 16384);    // 128*64 bf16 = 16384 B
    float*  sp = (float*)pool;               // [128][129] = 66048 B (after loop)
    float* p3l = (float*)(pool + 66048);     // 512 B

    const int t = threadIdx.x;
    const int lane = t & 63;
    const int wid = t >> 6;
    const int tM = blockIdx.y * 128;         // = batch * 128 channels
    const int tN = blockIdx.x * 128;
    const int wm2 = (wid & 1) * 64;
    const int wn2 = (wid >> 1) * 64;

    f32x4 acc[4][4];
    const f32x4 zero = {0.f, 0.f, 0.f, 0.f};
#pragma unroll
    for (int i = 0; i < 4; i++)
#pragma unroll
        for (int j = 0; j < 4; j++) acc[i][j] = zero;

    // staging: 4 issues per matrix; issue i covers rows i*32..i*32+31
    const int tr = t >> 3;                    // 0..31
    const int sc = (t & 7) ^ (tr & 7);        // swizzled global chunk
    const __bf16* pA[4];
    const __bf16* pB[4];
#pragma unroll
    for (int i = 0; i < 4; i++) {
        pA[i] = A + (size_t)(tM + i * 32 + tr) * 8192 + sc * 8;
        pB[i] = B + (size_t)(tN + i * 32 + tr) * bstride + sc * 8;
    }

    const int l15 = lane & 15;
    const int q = lane >> 4;
    int aoff[4], boff[4];
#pragma unroll
    for (int i = 0; i < 4; i++) {
        int row = wm2 + i * 16 + l15;
        aoff[i] = row * 64 + ((q ^ (row & 7)) * 8);
    }
#pragma unroll
    for (int j = 0; j < 4; j++) {
        int row = wn2 + j * 16 + l15;
        boff[j] = row * 64 + ((q ^ (row & 7)) * 8);
    }

    for (int it = 0; it < 128; it++) {
#pragma unroll
        for (int i = 0; i < 4; i++) load_lds16(pA[i], la + (i * 256 + t) * 8);
#pragma unroll
        for (int i = 0; i < 4; i++) load_lds16(pB[i], lb + (i * 256 + t) * 8);
#pragma unroll
        for (int i = 0; i < 4; i++) { pA[i] += 64; pB[i] += 64; }
        __syncthreads();
#pragma unroll
        for (int ks = 0; ks < 2; ks++) {
            bf16x8 af[4], bfr[4];
#pragma unroll
            for (int i = 0; i < 4; i++) af[i]  = *(const bf16x8*)(la + (aoff[i] ^ (ks << 5)));
#pragma unroll
            for (int j = 0; j < 4; j++) bfr[j] = *(const bf16x8*)(lb + (boff[j] ^ (ks << 5)));
#pragma unroll
            for (int i = 0; i < 4; i++)
#pragma unroll
                for (int j = 0; j < 4; j++)
                    acc[i][j] = __builtin_amdgcn_mfma_f32_16x16x32_bf16(af[i], bfr[j], acc[i][j], 0, 0, 0);
        }
        __syncthreads();
    }
    // loop ends with __syncthreads(): all LDS reads done, LDS-DMA drained ->
    // pool is safe to reuse.

    // ---- shortcut gather: sp[l][c] = sum_{k<cnt[tN+l]} s_t[b, idx, c]
    {
        const int l = t >> 1;                 // col-in-tile 0..127
        const int part = t & 1;               // channel half
        const int col = tN + l;
        const int n = cnt[col];
        const __bf16* base = s_t + ((size_t)blockIdx.y * 8192) * 128 + part * 64;
        float* spr = sp + l * 129 + part * 64;
        {
            const __bf16* row = base + (size_t)idx[col * 16] * 128;
#pragma unroll
            for (int j = 0; j < 8; j++) {
                bf16x8 v = *(const bf16x8*)(row + j * 8);
#pragma unroll
                for (int u = 0; u < 8; u++) spr[j * 8 + u] = (float)v[u];
            }
        }
        for (int k = 1; k < n; k++) {
            const __bf16* row = base + (size_t)idx[col * 16 + k] * 128;
#pragma unroll
            for (int j = 0; j < 8; j++) {
                bf16x8 v = *(const bf16x8*)(row + j * 8);
#pragma unroll
                for (int u = 0; u < 8; u++) spr[j * 8 + u] += (float)v[u];
            }
        }
        if (t < 128) p3l[t] = p3[t];
    }
    __syncthreads();

    // ---- fused combine epilogue
    const int quad4 = q * 4;
#pragma unroll
    for (int i = 0; i < 4; i++) {
        int gm = tM + wm2 + i * 16 + quad4;
#pragma unroll
        for (int j = 0; j < 4; j++) {
            int gn = tN + wn2 + j * 16 + l15;
            int colT = wn2 + j * 16 + l15;
#pragma unroll
            for (int r = 0; r < 4; r++) {
                int c = wm2 + i * 16 + quad4 + r;      // channel 0..127
                float v = acc[i][j][r];
                float pw = p3l[c];
                float y = (v >= 0.f) ? v : v * pw;
                y = (y - PM) * PIS;
                out[(size_t)(gm + r) * 4096 + gn] = sp[colT * 129 + c] * RHALF + y * RHALF;
            }
        }
    }
}

// ---------------------------------------------------------------- launch
extern "C" void kernel_launch(void* const* d_in, const int* in_sizes, int n_in,
                              void* d_out, int out_size, void* d_ws, size_t ws_size,
                              hipStream_t stream) {
    (void)in_sizes; (void)n_in; (void)out_size;
    const float* x    = (const float*)d_in[0];
    const float* conn = (const float*)d_in[1];
    const float* w1   = (const float*)d_in[2];
    const float* b1   = (const float*)d_in[3];
    const float* p1   = (const float*)d_in[4];
    const float* w2   = (const float*)d_in[5];
    const float* b2   = (const float*)d_in[6];
    const float* p2   = (const float*)d_in[7];
    const float* wm   = (const float*)d_in[8];
    const float* bm   = (const float*)d_in[9];
    const float* p3   = (const float*)d_in[10];
    const float* wsw  = (const float*)d_in[11];
    const float* bs   = (const float*)d_in[12];
    float* out = (float*)d_out;

    char* ws = (char*)d_ws;
    __bf16* h3  = (__bf16*)(ws);                          // 33,554,432 B
    __bf16* s_t = (__bf16*)(ws + 33554432);               // 33,554,432 B
    __bf16* W1p = (__bf16*)(ws + 67108864);               // 12,288
    __bf16* W2p = (__bf16*)(ws + 67108864 + 12288);       // 21,504
    __bf16* WMp = (__bf16*)(ws + 67108864 + 33792);       // 32,768
    __bf16* WSp = (__bf16*)(ws + 67108864 + 66560);       // 16,384
    int* idx = (int*)(ws + 67108864 + 82944);             // 262,144
    int* cnt = (int*)(ws + 67108864 + 82944 + 262144);    // 16,384
    const size_t connb_off = 67108864 + 82944 + 262144 + 16384;   // 67,470,336

    __bf16* connb;
    size_t  cstride;
    if (ws_size >= connb_off + (size_t)4096 * 8192 * 2) {
        connb = (__bf16*)(ws + connb_off);
        cstride = 8192;
    } else {
        connb = (__bf16*)const_cast<float*>(conn);
        cstride = 16384;   // bf16 row packed into first half of its fp32 row
    }

    k_prep<<<32, 256, 0, stream>>>(w1, w2, wm, wsw, W1p, W2p, WMp, WSp);
    k_cc<<<6144, 256, 0, stream>>>(conn, connb, cstride, cnt, idx,
                                   x, b1, p1, b2, p2, bm, bs,
                                   W1p, W2p, WMp, WSp, h3, s_t);
    k_gemm<<<dim3(4096 / 128, 2048 / 128), 256, 0, stream>>>(h3, connb, cstride,
                                                             out, s_t, idx, cnt, p3);
}